// Round 9
// baseline (607.863 us; speedup 1.0000x reference)
//
#include <hip/hip_runtime.h>

#define VOCAB 128
#define EMB   10
#define HID   20
#define BATCH 256
#define TLEN  2048
// tanh(x) = 1 - 2/(exp(2x)+1); v_exp_f32 computes 2^z, so fold 2*log2(e)
// into the weights/tables:  z = PRESCALE * (xw + W_hh h)
// RECURRENCE IS CARRIED IN r = 1/(2^z + 1)  (h = 1 - 2r):
//   z_j = [P(tok)_j] + sum_k (-2*PRESCALE*W_hh[j,k]) * r_k
// where P already contains PRESCALE*(biases + emb.W_ih + sum_k W_hh[j,k]).
// Consumers fold h=1-2r into their weights: out = (b+sum_j Wout) - 2*Wout.r
#define PRESCALE 2.8853900817779268f

// ---------------------------------------------------------------------------
// Kernel A: P[v][j] = PRESCALE*(b_ih[j]+b_hh[j]+sum_e W_ih[j,e]*emb[v,e]
//                              + sum_k W_hh[j,k])
// ---------------------------------------------------------------------------
__global__ __launch_bounds__(256)
void build_table(const float* __restrict__ emb, const float* __restrict__ W_ih,
                 const float* __restrict__ W_hh,
                 const float* __restrict__ b_ih, const float* __restrict__ b_hh,
                 float* __restrict__ P) {
    int idx = blockIdx.x * blockDim.x + threadIdx.x;
    if (idx < VOCAB * HID) {
        int v = idx / HID, j = idx % HID;
        float acc = b_ih[j] + b_hh[j];
        #pragma unroll
        for (int e = 0; e < EMB; ++e)
            acc = fmaf(W_ih[j * EMB + e], emb[v * EMB + e], acc);
        float wsum = 0.f;
        #pragma unroll
        for (int k = 0; k < HID; ++k) wsum += W_hh[j * HID + k];
        P[idx] = (acc + wsum) * PRESCALE;
    }
}

// ---------------------------------------------------------------------------
// Fused kernel: one block per TWO batch rows, 8 waves (512 threads).
// KEY IDEA (m114: co-resident waves overlap, time = max not sum): waves are
// assigned to SIMDs round-robin (wave i -> SIMD i%4), so making waves 0 AND 4
// the producers puts BOTH serial chains on SIMD 0. Hardware multithreading
// fills each chain's issue stalls (readlane/trans hazards, dep latency) with
// the other chain's instructions - no compiler cooperation needed (the R8
// single-wave software interleave failed: stalls block the whole wave).
//   wave 0: row A's recurrence (identical chain to the 207us R5 version)
//   wave 4: row B's recurrence
//   waves 1,2,3,5,6,7: consume chunk c-1 (128 t-rows) while producers make c.
// Worst case (mapping not i%4): two independent R5-style chains -> flat 207us.
// ---------------------------------------------------------------------------
#define RNN_STEP(XW) { \
    const int ri_ = __float_as_int(r); \
    float bc[HID]; \
    _Pragma("unroll") \
    for (int k = 0; k < HID; ++k) \
        bc[k] = __int_as_float(__builtin_amdgcn_readlane(ri_, k)); \
    float a0 = (XW), a1 = 0.f, a2 = 0.f, a3 = 0.f; \
    _Pragma("unroll") \
    for (int k = 0; k < HID; k += 4) { \
        a0 = fmaf(w[k + 0], bc[k + 0], a0); \
        a1 = fmaf(w[k + 1], bc[k + 1], a1); \
        a2 = fmaf(w[k + 2], bc[k + 2], a2); \
        a3 = fmaf(w[k + 3], bc[k + 3], a3); } \
    float z_ = (a0 + a1) + (a2 + a3); \
    float u_ = __builtin_amdgcn_exp2f(z_); \
    r = __builtin_amdgcn_rcpf(u_ + 1.0f); }

__global__ __launch_bounds__(512)
void rnn_fused(const int* __restrict__ tokens, const float* __restrict__ W_hh,
               const float* __restrict__ P, const float* __restrict__ W_out,
               const float* __restrict__ b_out, float* __restrict__ out) {
    __shared__ float Pl[VOCAB * HID];                 // 10240 B
    __shared__ __align__(16) int tokA[TLEN + 16];     //  8256 B
    __shared__ __align__(16) int tokB[TLEN + 16];     //  8256 B
    __shared__ float hbA[2 * 64 * 32];                //  8192 B x2: r-values,
    __shared__ float hbB[2 * 64 * 32];                //  row stride 32, cols 0-19
    // total static LDS: 59520 B (< 64 KiB, same budget as the version that ran)
    const int tid  = threadIdx.x;
    const int lane = tid & 63;
    const int wid  = tid >> 6;
    const int blk  = blockIdx.x;
    const int bA   = 2 * blk, bB = 2 * blk + 1;
    const bool isProd = (wid == 0) | (wid == 4);      // both land on SIMD 0 (i%4)

    // cooperative staging (all 512 threads; TLEN/4 = 512 -> one int4 each)
    for (int i = tid; i < VOCAB * HID; i += 512) Pl[i] = P[i];
    {
        const int4* srcA = (const int4*)(tokens + (size_t)bA * TLEN);
        const int4* srcB = (const int4*)(tokens + (size_t)bB * TLEN);
        ((int4*)tokA)[tid] = srcA[tid];
        ((int4*)tokB)[tid] = srcB[tid];
    }
    if (tid < 16) { tokA[TLEN + tid] = 0; tokB[TLEN + tid] = 0; }

    // per-role register init (before the staging barrier: global reads only)
    const int j = lane < HID ? lane : HID - 1;        // producer: clamp, dup row 19
    float w[HID], wB[HID];
    float bo0 = 0.f, bo1 = 0.f;
    if (isProd) {
        #pragma unroll
        for (int k = 0; k < HID; ++k)
            w[k] = W_hh[j * HID + k] * (-2.0f * PRESCALE);
    } else {
        const int v0 = 2 * lane, v1 = 2 * lane + 1;
        float s0 = 0.f, s1 = 0.f;
        #pragma unroll
        for (int k = 0; k < HID; ++k) {
            float wa = W_out[v0 * HID + k], wb = W_out[v1 * HID + k];
            s0 += wa; s1 += wb;
            w[k]  = -2.0f * wa;
            wB[k] = -2.0f * wb;
        }
        bo0 = b_out[v0] + s0; bo1 = b_out[v1] + s1;
    }
    __syncthreads();

    // producer pipeline prologue: tokens for steps 0..15, xw for steps 0..7
    const int* tk     = (wid == 0) ? tokA : tokB;     // producer's token buffer
    float*     pbuf   = (wid == 0) ? hbA  : hbB;      // producer's output buffer
    float r = 0.5f;                                    // h0 = 0  <=>  r0 = 0.5
    int4 ta, tb, tkc, tkd;
    float xw0[4], xw1[4];
    if (isProd) {
        __builtin_amdgcn_s_setprio(1);                 // critical-path waves
        ta  = *(const int4*)&tk[0];
        tb  = *(const int4*)&tk[4];
        tkc = *(const int4*)&tk[8];
        tkd = *(const int4*)&tk[12];
        xw0[0] = Pl[ta.x * HID + j]; xw0[1] = Pl[ta.y * HID + j];
        xw0[2] = Pl[ta.z * HID + j]; xw0[3] = Pl[ta.w * HID + j];
        xw1[0] = Pl[tb.x * HID + j]; xw1[1] = Pl[tb.y * HID + j];
        xw1[2] = Pl[tb.z * HID + j]; xw1[3] = Pl[tb.w * HID + j];
    }

    // 33-iteration pipeline: iter c -> producers make chunk c (one row each),
    // consumers project chunk c-1 from the other LDS buffer half.
    for (int c = 0; c < 33; ++c) {
        if (isProd && c < 32) {
            float* hb = pbuf + (c & 1) * (64 * 32) + lane;  // col=lane (<32 stored)
            for (int t8 = 0; t8 < 64; t8 += 8) {
                const int t = c * 64 + t8;
                float* hrow = hb + t8 * 32;
                // ---- steps t..t+3 ----
                RNN_STEP(xw0[0]); if (lane < 32) hrow[0 * 32] = r;
                RNN_STEP(xw0[1]); if (lane < 32) hrow[1 * 32] = r;
                RNN_STEP(xw0[2]); if (lane < 32) hrow[2 * 32] = r;
                RNN_STEP(xw0[3]); if (lane < 32) hrow[3 * 32] = r;
                // refill xw0 for steps t+8..t+11 (latency hidden by next steps)
                float n0[4] = {Pl[tkc.x * HID + j], Pl[tkc.y * HID + j],
                               Pl[tkc.z * HID + j], Pl[tkc.w * HID + j]};
                tkc = *(const int4*)&tk[t + 16];
                // ---- steps t+4..t+7 ----
                RNN_STEP(xw1[0]); if (lane < 32) hrow[4 * 32] = r;
                RNN_STEP(xw1[1]); if (lane < 32) hrow[5 * 32] = r;
                RNN_STEP(xw1[2]); if (lane < 32) hrow[6 * 32] = r;
                RNN_STEP(xw1[3]); if (lane < 32) hrow[7 * 32] = r;
                // refill xw1 for steps t+12..t+15
                float n1[4] = {Pl[tkd.x * HID + j], Pl[tkd.y * HID + j],
                               Pl[tkd.z * HID + j], Pl[tkd.w * HID + j]};
                tkd = *(const int4*)&tk[t + 20];
                #pragma unroll
                for (int u = 0; u < 4; ++u) { xw0[u] = n0[u]; xw1[u] = n1[u]; }
            }
        }
        if (!isProd && c > 0) {
            const int cc   = c - 1;
            const int cwid = (wid < 4) ? wid - 1 : wid - 2;   // 0..5
            const int boff = (cc & 1) * (64 * 32);
            for (int rr = cwid; rr < 128; rr += 6) {
                const int  row = rr & 63;
                const bool isB = rr >= 64;
                const float* hr = (isB ? hbB : hbA) + boff + row * 32;
                const int  bb  = isB ? bB : bA;
                float* op = out + ((size_t)bb * TLEN + (size_t)cc * 64 + row) * VOCAB
                                + 2 * lane;
                float a0 = bo0, a1 = bo1;
                #pragma unroll
                for (int k = 0; k < HID; k += 4) {
                    float4 hv = *(const float4*)(hr + k);   // wave-uniform broadcast
                    a0 = fmaf(hv.x, w[k + 0], a0); a1 = fmaf(hv.x, wB[k + 0], a1);
                    a0 = fmaf(hv.y, w[k + 1], a0); a1 = fmaf(hv.y, wB[k + 1], a1);
                    a0 = fmaf(hv.z, w[k + 2], a0); a1 = fmaf(hv.z, wB[k + 2], a1);
                    a0 = fmaf(hv.w, w[k + 3], a0); a1 = fmaf(hv.w, wB[k + 3], a1);
                }
                *(float2*)op = make_float2(a0, a1);
            }
        }
        __syncthreads();
    }
}

extern "C" void kernel_launch(void* const* d_in, const int* in_sizes, int n_in,
                              void* d_out, int out_size, void* d_ws, size_t ws_size,
                              hipStream_t stream) {
    const int*   inputs = (const int*)  d_in[0];
    const float* emb    = (const float*)d_in[1];
    const float* W_ih   = (const float*)d_in[2];
    const float* W_hh   = (const float*)d_in[3];
    const float* b_ih   = (const float*)d_in[4];
    const float* b_hh   = (const float*)d_in[5];
    const float* W_out  = (const float*)d_in[6];
    const float* b_out  = (const float*)d_in[7];
    float* out = (float*)d_out;

    float* P = (float*)d_ws;   // 10240 B table

    build_table<<<(VOCAB * HID + 255) / 256, 256, 0, stream>>>(emb, W_ih, W_hh,
                                                               b_ih, b_hh, P);
    rnn_fused<<<BATCH / 2, 512, 0, stream>>>(inputs, W_hh, P, W_out, b_out, out);
}